// Round 1
// baseline (590.278 us; speedup 1.0000x reference)
//
#include <hip/hip_runtime.h>

// Problem constants
#define PAD_ID 0
#define NTOK   16384          // B*L = 16*1024
#define DIM    768
#define KLAT   5000
#define KPAD   5024           // 157*32, zero-padded latent rows
#define NSTEP  157            // 5024/32
#define TILE_SH 24576         // shorts per 32x768 tile (48 KB)
#define TOKB   32             // tokens per block (512 blocks -> 2 blocks/CU)

typedef float f32x4 __attribute__((ext_vector_type(4)));
typedef __bf16 bf16x8 __attribute__((ext_vector_type(8)));

__device__ __forceinline__ unsigned short f2bf(float f) {
    unsigned int u = __float_as_uint(f);
    u += 0x7fffu + ((u >> 16) & 1u);   // RNE
    return (unsigned short)(u >> 16);
}
__device__ __forceinline__ float bf2f(unsigned short h) {
    return __uint_as_float(((unsigned int)h) << 16);
}
__device__ __forceinline__ void async_cp16(const unsigned short* g, unsigned short* l) {
    __builtin_amdgcn_global_load_lds(
        (const __attribute__((address_space(1))) unsigned int*)g,
        (__attribute__((address_space(3))) unsigned int*)l, 16, 0, 0);
}

// ---------------------------------------------------------------------------
// Kernel 0a: latent -> latbS, bf16, MFMA-A-fragment order per 32-row tile:
//   latbS[t][kf][h][lane][j] = Lat[t*32 + h*16 + (lane&15)][kf*32 + (lane>>4)*8 + j]
// S-phase LDS image is then frag-linear: ds_read_b128 at stride-1, 0 conflicts.
// ---------------------------------------------------------------------------
__global__ __launch_bounds__(256) void cvt_latS(const float* __restrict__ latent,
                                                unsigned short* __restrict__ latbS) {
    int g = blockIdx.x * 256 + threadIdx.x;          // one 8-short frag per thread
    if (g >= NSTEP * 24 * 2 * 64) return;
    int lane = g & 63; int rest = g >> 6;            // [t][kf][h]
    int h = rest & 1;  int kfr = rest >> 1;
    int kf = kfr % 24; int t  = kfr / 24;
    int row = t * 32 + h * 16 + (lane & 15);
    int col = kf * 32 + (lane >> 4) * 8;
    float4 v0 = make_float4(0.f,0.f,0.f,0.f), v1 = v0;
    if (row < KLAT) {
        v0 = *(const float4*)(latent + (long)row * DIM + col);
        v1 = *(const float4*)(latent + (long)row * DIM + col + 4);
    }
    uint4 o;
    o.x = (unsigned)f2bf(v0.x) | ((unsigned)f2bf(v0.y) << 16);
    o.y = (unsigned)f2bf(v0.z) | ((unsigned)f2bf(v0.w) << 16);
    o.z = (unsigned)f2bf(v1.x) | ((unsigned)f2bf(v1.y) << 16);
    o.w = (unsigned)f2bf(v1.z) | ((unsigned)f2bf(v1.w) << 16);
    *(uint4*)(latbS + (size_t)g * 8) = o;
}

// ---------------------------------------------------------------------------
// Kernel 0b: latent -> latbT, bf16, d-major per tile:
//   latbT[t][d][kk] = Lat[t*32 + kk][d]   (tile = 768x32 = 48 KB)
// O-phase B-frags become fully-coalesced global dwordx4 direct to registers.
// ---------------------------------------------------------------------------
__global__ __launch_bounds__(256) void cvt_latT(const float* __restrict__ latent,
                                                unsigned short* __restrict__ latbT) {
    int g = blockIdx.x * 256 + threadIdx.x;          // one 8-short group
    if (g >= NSTEP * DIM * 4) return;
    int kk8 = g & 3; int rest = g >> 2;
    int d = rest % DIM; int t = rest / DIM;
    int kk0 = kk8 * 8;
    unsigned short v[8];
    #pragma unroll
    for (int j = 0; j < 8; ++j) {
        int row = t * 32 + kk0 + j;
        v[j] = (row < KLAT) ? f2bf(latent[(long)row * DIM + d]) : (unsigned short)0;
    }
    *(uint4*)(latbT + (size_t)g * 8) = *(uint4*)v;
}

// ---------------------------------------------------------------------------
// Kernel 1: lang_emb = tanh(masked-mean of char embeddings), stored bf16.
// ---------------------------------------------------------------------------
__global__ __launch_bounds__(192) void build_lang(const int* __restrict__ x,
                                                  const float* __restrict__ cemb,
                                                  unsigned short* __restrict__ langb) {
    int tok = blockIdx.x;
    int t = threadIdx.x;
    const int* xs = x + tok * 8;
    int ids[8]; int cnt = 0;
    #pragma unroll
    for (int c = 0; c < 8; ++c) { ids[c] = xs[c]; cnt += (ids[c] != PAD_ID); }
    float4 acc = make_float4(0.f, 0.f, 0.f, 0.f);
    #pragma unroll
    for (int c = 0; c < 8; ++c) {
        if (ids[c] != PAD_ID) {
            float4 v = *(const float4*)(cemb + (long)ids[c] * DIM + t * 4);
            acc.x += v.x; acc.y += v.y; acc.z += v.z; acc.w += v.w;
        }
    }
    float cntf = (float)max(cnt, 1);
    unsigned int u0 = (unsigned int)f2bf(tanhf(acc.x / cntf)) |
                      ((unsigned int)f2bf(tanhf(acc.y / cntf)) << 16);
    unsigned int u1 = (unsigned int)f2bf(tanhf(acc.z / cntf)) |
                      ((unsigned int)f2bf(tanhf(acc.w / cntf)) << 16);
    *(uint2*)(langb + tok * DIM + t * 4) = make_uint2(u0, u1);
}

// ---------------------------------------------------------------------------
// Kernel 2 (v2): 32 tokens/block, 512 blocks -> 2 blocks/CU co-resident.
// Wave roles: tt = w&1 (token tile, 16 tokens), lt = w>>1 (lat tile of step).
// S-phase: wave computes 16 tok x 16 lat via 24 MFMA (24 A ds_reads, Q in regs,
//   two accumulation chains for dep-latency robustness).
// O-phase: wave computes 32 tok x 192 d (accO[2][12] = 96 regs, was 192).
// bO prefetched in 3 staggered rounds of 4 to cap register pressure ~250.
// __launch_bounds__(256,2) pins allocator to 256 so 2 blocks/CU fit.
// ---------------------------------------------------------------------------
__global__ __launch_bounds__(256, 2) void fused_sde(
        const int* __restrict__ x, const float* __restrict__ cemb,
        const unsigned short* __restrict__ langb,
        const unsigned short* __restrict__ latbS,
        const unsigned short* __restrict__ latbT,
        float* __restrict__ out) {
    __shared__ unsigned short sLat[TILE_SH];   // 48 KB, frag-linear image
    __shared__ unsigned short sP[TOKB * 40];   // P, row-padded (+8) for banks
    __shared__ float sL[2][TOKB];

    const int tid  = threadIdx.x;
    const int w    = tid >> 6;
    const int lane = tid & 63;
    const int ln   = lane & 15;
    const int quad = lane >> 4;
    const int tt   = w & 1;          // token tile (0..1)
    const int lt   = w >> 1;         // lat tile within step (0..1)
    const int m0   = blockIdx.x * TOKB;

    // Q fragments (B-operand for S^T): token = m0 + tt*16 + ln
    uint4 qf[24];
    {
        const unsigned short* qr = langb + (m0 + tt * 16 + ln) * DIM;
        #pragma unroll
        for (int kf = 0; kf < 24; ++kf)
            qf[kf] = *(const uint4*)(qr + kf * 32 + quad * 8);
    }

    f32x4 accO[2][12];
    #pragma unroll
    for (int mt = 0; mt < 2; ++mt)
        #pragma unroll
        for (int dt = 0; dt < 12; ++dt)
            accO[mt][dt] = (f32x4){0.f, 0.f, 0.f, 0.f};
    float lpart = 0.f;

    // Prologue: DMA tile 0 into LDS
    #pragma unroll
    for (int i = 0; i < 12; ++i)
        async_cp16(latbS + ((size_t)i * 256 + tid) * 8,
                   sLat + (i * 256 + (tid & ~63)) * 8);
    __syncthreads();   // drain -> tile 0 ready

    const int aBase = lt * 64 + lane;               // frag slot within kf group
    const int bBase = (w * 192 + ln) * 32 + quad * 8;

    for (int s = 0; s < NSTEP; ++s) {
        const unsigned short* bt = latbT + (size_t)s * TILE_SH;

        // O-phase B frags, round 1 (dt 0..3): hidden under S-phase
        uint4 bO0[4];
        #pragma unroll
        for (int dt = 0; dt < 4; ++dt)
            bO0[dt] = *(const uint4*)(bt + bBase + dt * 512);

        // ---- S^T phase: 24 MFMA, two independent chains ----
        f32x4 sva = {0.f,0.f,0.f,0.f}, svb = {0.f,0.f,0.f,0.f};
        #pragma unroll
        for (int kp = 0; kp < 12; ++kp) {
            bf16x8 a0 = *(const bf16x8*)&sLat[((2 * kp)     * 128 + aBase) * 8];
            bf16x8 a1 = *(const bf16x8*)&sLat[((2 * kp + 1) * 128 + aBase) * 8];
            bf16x8 b0 = *(const bf16x8*)&qf[2 * kp];
            bf16x8 b1 = *(const bf16x8*)&qf[2 * kp + 1];
            sva = __builtin_amdgcn_mfma_f32_16x16x32_bf16(a0, b0, sva, 0, 0, 0);
            svb = __builtin_amdgcn_mfma_f32_16x16x32_bf16(a1, b1, svb, 0, 0, 0);
        }

        // round 2 (dt 4..7)
        uint4 bO1[4];
        #pragma unroll
        for (int dt = 0; dt < 4; ++dt)
            bO1[dt] = *(const uint4*)(bt + bBase + (dt + 4) * 512);

        // ---- exp (no max-sub), P write (one b64), l partial ----
        {
            const int lat0 = s * 32 + lt * 16 + quad * 4;
            f32x4 sv = sva + svb;
            float e0 = (lat0     < KLAT) ? __expf(sv[0]) : 0.f;
            float e1 = (lat0 + 1 < KLAT) ? __expf(sv[1]) : 0.f;
            float e2 = (lat0 + 2 < KLAT) ? __expf(sv[2]) : 0.f;
            float e3 = (lat0 + 3 < KLAT) ? __expf(sv[3]) : 0.f;
            lpart += (e0 + e1) + (e2 + e3);
            unsigned int p01 = (unsigned)f2bf(e0) | ((unsigned)f2bf(e1) << 16);
            unsigned int p23 = (unsigned)f2bf(e2) | ((unsigned)f2bf(e3) << 16);
            *(uint2*)&sP[(tt * 16 + ln) * 40 + lt * 16 + quad * 4] =
                make_uint2(p01, p23);
        }
        __syncthreads();   // S-reads of sLat done; sP published

        // P A-frags (all 32 tokens) + round 3 (dt 8..11)
        bf16x8 pA0 = *(const bf16x8*)&sP[ln * 40 + quad * 8];
        bf16x8 pA1 = *(const bf16x8*)&sP[(16 + ln) * 40 + quad * 8];
        uint4 bO2[4];
        #pragma unroll
        for (int dt = 0; dt < 4; ++dt)
            bO2[dt] = *(const uint4*)(bt + bBase + (dt + 8) * 512);

        // DMA next tile into sLat (drained at loop-end barrier, hidden by O)
        {
            int nt = (s + 1 < NSTEP) ? s + 1 : 0;
            const unsigned short* gs = latbS + (size_t)nt * TILE_SH;
            #pragma unroll
            for (int i = 0; i < 12; ++i)
                async_cp16(gs + (i * 256 + tid) * 8,
                           sLat + (i * 256 + (tid & ~63)) * 8);
        }

        // ---- O phase: O[tok][d] += P[tok][lat] * Lat[lat][d] ----
        #pragma unroll
        for (int dt = 0; dt < 4; ++dt) {
            bf16x8 b = *(const bf16x8*)&bO0[dt];
            accO[0][dt] = __builtin_amdgcn_mfma_f32_16x16x32_bf16(pA0, b, accO[0][dt], 0, 0, 0);
            accO[1][dt] = __builtin_amdgcn_mfma_f32_16x16x32_bf16(pA1, b, accO[1][dt], 0, 0, 0);
        }
        #pragma unroll
        for (int dt = 0; dt < 4; ++dt) {
            bf16x8 b = *(const bf16x8*)&bO1[dt];
            accO[0][dt + 4] = __builtin_amdgcn_mfma_f32_16x16x32_bf16(pA0, b, accO[0][dt + 4], 0, 0, 0);
            accO[1][dt + 4] = __builtin_amdgcn_mfma_f32_16x16x32_bf16(pA1, b, accO[1][dt + 4], 0, 0, 0);
        }
        #pragma unroll
        for (int dt = 0; dt < 4; ++dt) {
            bf16x8 b = *(const bf16x8*)&bO2[dt];
            accO[0][dt + 8] = __builtin_amdgcn_mfma_f32_16x16x32_bf16(pA0, b, accO[0][dt + 8], 0, 0, 0);
            accO[1][dt + 8] = __builtin_amdgcn_mfma_f32_16x16x32_bf16(pA1, b, accO[1][dt + 8], 0, 0, 0);
        }
        __syncthreads();   // drains DMA (tile s+1 ready); sP reads done
    }

    // softmax denominator: reduce over quads (token invariant under xor 16/32),
    // then cross-latTile sum via sL.
    lpart += __shfl_xor(lpart, 16, 64);
    lpart += __shfl_xor(lpart, 32, 64);
    if (lane < 16) sL[lt][tt * 16 + lane] = lpart;
    __syncthreads();

    // epilogue: /l + lang + special-token override, fp32 out
    #pragma unroll
    for (int mt = 0; mt < 2; ++mt) {
        int tl0 = mt * 16 + quad * 4;
        float linv[4]; int fid[4];
        #pragma unroll
        for (int r = 0; r < 4; ++r) {
            linv[r] = 1.0f / (sL[0][tl0 + r] + sL[1][tl0 + r]);
            fid[r]  = x[(m0 + tl0 + r) * 8];
        }
        #pragma unroll
        for (int dt = 0; dt < 12; ++dt) {
            int d = w * 192 + dt * 16 + ln;
            #pragma unroll
            for (int r = 0; r < 4; ++r) {
                int tok = m0 + tl0 + r;
                float v = accO[mt][dt][r] * linv[r] + bf2f(langb[tok * DIM + d]);
                if (fid[r] < 4) v = cemb[fid[r] * DIM + d];  // PAD/CLS/SEP/UNK
                out[tok * DIM + d] = v;
            }
        }
    }
}

// ---------------------------------------------------------------------------
extern "C" void kernel_launch(void* const* d_in, const int* in_sizes, int n_in,
                              void* d_out, int out_size, void* d_ws, size_t ws_size,
                              hipStream_t stream) {
    const int*   x      = (const int*)d_in[0];     // (16,1024,8) int
    const float* cemb   = (const float*)d_in[1];   // (30000,768) f32
    const float* latent = (const float*)d_in[2];   // (5000,768) f32
    float* out = (float*)d_out;                    // (16,1024,768) f32

    unsigned short* langb = (unsigned short*)d_ws;                          // 25.2 MB
    unsigned short* latbS = langb + (size_t)NTOK * DIM;                     // 7.7 MB
    unsigned short* latbT = latbS + (size_t)NSTEP * TILE_SH;                // 7.7 MB

    int nS = NSTEP * 24 * 2 * 64;        // frag groups in latbS
    int nT = NSTEP * DIM * 4;            // 8-short groups in latbT
    cvt_latS<<<(nS + 255) / 256, 256, 0, stream>>>(latent, latbS);
    cvt_latT<<<(nT + 255) / 256, 256, 0, stream>>>(latent, latbT);
    build_lang<<<NTOK, 192, 0, stream>>>(x, cemb, langb);
    fused_sde<<<NTOK / TOKB, 256, 0, stream>>>(x, cemb, langb, latbS, latbT, out);
}